// Round 1
// baseline (564.911 us; speedup 1.0000x reference)
//
#include <hip/hip_runtime.h>
#include <math.h>

#define NB 16
#define NH 1024
#define NT 4096
#define CD 8
#define CS 1024
#define NBT (NB*NT)
#define TPB 128              // t-columns per block
#define GRID (NBT/TPB)       // 512 blocks
#define MARGIN 1e-3f         // fp32 top-2 margin; fp32 dist abs-error bound ~6e-6 -> 160x safety

// ---------------- K0: prepare tables in workspace ----------------
__global__ __launch_bounds__(256) void k0_prep(
    const float* __restrict__ w,      // in_proj_w [CD][NH]
    const float* __restrict__ bias,   // in_proj_b [CD]
    const float* __restrict__ cb,     // codebook [CS][CD]
    double* __restrict__ Wt,          // out: [NH][CD] fp64
    double* __restrict__ biasd,       // out: [CD]
    double* __restrict__ cbn,         // out: normalized codebook [CS][CD] fp64
    double* __restrict__ cbn2,        // out: sum(cbn^2) [CS] fp64
    float*  __restrict__ cbnf,        // out: normalized codebook fp32 [CS][CD]
    float*  __restrict__ cbn2f,       // out: sum fp32 [CS]
    double* __restrict__ lossacc,     // zeroed
    unsigned* __restrict__ donecnt)   // zeroed
{
    int g = blockIdx.x * 256 + threadIdx.x;   // grid = 32*256 = 8192
    if (g < CD * NH) {
        int h = g >> 3, d = g & 7;
        Wt[g] = (double)w[d * NH + h];
    }
    if (g < CS) {
        double v[CD];
        double s = 0.0;
        #pragma unroll
        for (int j = 0; j < CD; j++) { v[j] = (double)cb[g * CD + j]; s += v[j] * v[j]; }
        double n = sqrt(s);
        double m = fmax(n, 1e-12);
        double s2 = 0.0;
        #pragma unroll
        for (int j = 0; j < CD; j++) {
            double q = v[j] / m;              // replicate x / max(n,eps) exactly
            cbn[g * CD + j] = q;
            cbnf[g * CD + j] = (float)q;
            s2 += q * q;
        }
        cbn2[g] = s2;
        cbn2f[g] = (float)s2;
    }
    if (g < CD) biasd[g] = (double)bias[g];
    if (g == 0) { *lossacc = 0.0; *donecnt = 0u; }
}

// ---------------- fused: proj -> argmax -> out ----------------
// block (64,8)=512 threads, 512 blocks. Each block owns 128 consecutive t of one b.
struct __align__(16) Smem {
    double projs[TPB][CD];                 // 8 KB, persists A -> C
    union {
        double red[8][64][2][4];           // 32 KB, phase-A cross-wave reduce (2 rounds of 4 d)
        struct {
            float  pn2f[TPB][CD];          // 4 KB   query 2*p/m in fp32
            float  bv4[4][TPB];            // per-chunk best
            float  sv4[4][TPB];            // per-chunk second-best
            int    bi4[4][TPB];            // per-chunk best index
            int    bfin[TPB];              // final index per row
            int    flag[TPB];              // needs-fp64-recheck
            float  qf[TPB][CD];            // 4 KB   q_st fp32 for phase C
        } b;
    } u;
};   // total 40 KB -> 4 blocks/CU LDS cap; grid puts 2/CU

__global__ __launch_bounds__(512) void k_fused(
    const float*  __restrict__ x,       // hidden [NB][NH][NT]
    const double* __restrict__ Wt,      // [NH][CD]
    const double* __restrict__ biasd,   // [CD]
    const double* __restrict__ cbn,     // [CS][CD] fp64 (fallback)
    const double* __restrict__ cbn2,    // [CS]     fp64 (fallback)
    const float*  __restrict__ cbnf,    // [CS][CD] fp32
    const float*  __restrict__ cbn2f,   // [CS]     fp32
    const float*  __restrict__ cb,      // original codebook fp32 [CS][CD]
    const float*  __restrict__ wo,      // out_proj_w [NH][CD]
    const float*  __restrict__ bo,      // out_proj_b [NH]
    double* __restrict__ lossacc,
    unsigned* __restrict__ donecnt,
    float* __restrict__ out,            // [NB][NH][NT]
    float* __restrict__ lossout,        // 2 floats
    float* __restrict__ idxf,           // [NBT]
    float* __restrict__ projf)          // [NB][CD][NT]
{
    __shared__ Smem sm;
    const int tx  = threadIdx.x;
    const int ty  = threadIdx.y;
    const int tid = ty * 64 + tx;
    const int bt0 = blockIdx.x * TPB;
    const int b   = bt0 >> 12;            // NT = 4096
    const int t0  = bt0 & (NT - 1);

    // ================= Phase A: proj (fp64, identical accumulation order to prior K1) =================
    const int h0 = __builtin_amdgcn_readfirstlane(ty * 128);
    const float* xp = x + ((size_t)b * NH) * NT + t0 + tx * 2;

    double acc[2][CD];
    #pragma unroll
    for (int tt = 0; tt < 2; tt++)
        #pragma unroll
        for (int d = 0; d < CD; d++) acc[tt][d] = 0.0;

    for (int i = 0; i < 128; i += 8) {
        float2 xv[8];
        #pragma unroll
        for (int j = 0; j < 8; j++) xv[j] = *(const float2*)(xp + (size_t)(h0 + i + j) * NT);
        #pragma unroll
        for (int j = 0; j < 8; j++) {
            const double* wr = Wt + (size_t)(h0 + i + j) * CD;   // wave-uniform -> scalar loads
            const double x0 = (double)xv[j].x;
            const double x1 = (double)xv[j].y;
            #pragma unroll
            for (int d = 0; d < CD; d++) {
                acc[0][d] = fma(x0, wr[d], acc[0][d]);
                acc[1][d] = fma(x1, wr[d], acc[1][d]);
            }
        }
    }

    // cross-ty reduce in two 4-d rounds (red = 32 KB per round)
    const int tl = tid & (TPB - 1);                 // 0..127 : local t
    const int dg = __builtin_amdgcn_readfirstlane(tid >> 7);  // 0..3, wave-uniform

    // round 1: d = 0..3
    #pragma unroll
    for (int tt = 0; tt < 2; tt++)
        #pragma unroll
        for (int dd = 0; dd < 4; dd++) sm.u.red[ty][tx][tt][dd] = acc[tt][dd];
    __syncthreads();
    {
        const int d = dg;
        double s = 0.0;
        #pragma unroll
        for (int j = 0; j < 8; j++) s += sm.u.red[j][tl >> 1][tl & 1][dg];
        s += biasd[d];
        sm.projs[tl][d] = s;
        projf[((size_t)b * CD + d) * NT + t0 + tl] = (float)s;
    }
    __syncthreads();
    // round 2: d = 4..7
    #pragma unroll
    for (int tt = 0; tt < 2; tt++)
        #pragma unroll
        for (int dd = 0; dd < 4; dd++) sm.u.red[ty][tx][tt][dd] = acc[tt][4 + dd];
    __syncthreads();
    {
        const int d = 4 + dg;
        double s = 0.0;
        #pragma unroll
        for (int j = 0; j < 8; j++) s += sm.u.red[j][tl >> 1][tl & 1][dg];
        s += biasd[d];
        sm.projs[tl][d] = s;
        projf[((size_t)b * CD + d) * NT + t0 + tl] = (float)s;
    }
    __syncthreads();   // projs complete; red region free for phase-B structs

    // ================= Phase B: argmax (fp32 scan + certified fp64 fallback) =================
    if (tid < TPB) {
        double p[CD];
        double s = 0.0;
        #pragma unroll
        for (int d = 0; d < CD; d++) { p[d] = sm.projs[tid][d]; s += p[d] * p[d]; }
        const double m = fmax(sqrt(s), 1e-12);
        #pragma unroll
        for (int d = 0; d < CD; d++) sm.u.b.pn2f[tid][d] = (float)(2.0 * (p[d] / m));
    }
    __syncthreads();

    {   // fp32 scan: 4 chunk-threads per row, 256 codes each; chunk index wave-uniform -> scalar cb loads
        const int r = tid & (TPB - 1);
        const int cc = tid >> 7;
        const int cbase = __builtin_amdgcn_readfirstlane(cc * 256);
        float pn[CD];
        #pragma unroll
        for (int d = 0; d < CD; d++) pn[d] = sm.u.b.pn2f[r][d];
        float best = -3.4e38f, second = -3.4e38f;
        int bidx = cbase;
        #pragma unroll 4
        for (int c = 0; c < 256; c++) {
            const float* cr = cbnf + (size_t)(cbase + c) * CD;   // wave-uniform -> scalar loads
            float dot = cbn2f[cbase + c];
            #pragma unroll
            for (int d = 0; d < CD; d++) dot = fmaf(pn[d], cr[d], dot);
            second = fmaxf(second, fminf(dot, best));            // top-2 tracking
            if (dot > best) { best = dot; bidx = cbase + c; }    // strict > keeps first max
        }
        sm.u.b.bv4[cc][r] = best;
        sm.u.b.sv4[cc][r] = second;
        sm.u.b.bi4[cc][r] = bidx;
    }
    __syncthreads();

    if (tid < TPB) {   // combine 4 chunks (ascending -> first-max tie rule preserved)
        float bv = sm.u.b.bv4[0][tid];
        float sv = sm.u.b.sv4[0][tid];
        int   bi = sm.u.b.bi4[0][tid];
        #pragma unroll
        for (int k = 1; k < 4; k++) {
            const float bk = sm.u.b.bv4[k][tid];
            const float sk = sm.u.b.sv4[k][tid];
            const int   ik = sm.u.b.bi4[k][tid];
            sv = fmaxf(fmaxf(sv, sk), fminf(bv, bk));
            if (bk > bv) { bv = bk; bi = ik; }
        }
        sm.u.b.bfin[tid] = bi;
        sm.u.b.flag[tid] = (bv - sv <= MARGIN) ? 1 : 0;
    }
    __syncthreads();

    // fp64 fallback for near-tie rows: bit-identical to the previous all-fp64 K2 decision
    for (int rr = 0; rr < 16; rr++) {
        const int r = ty * 16 + rr;
        if (sm.u.b.flag[r]) {                       // wave-uniform branch
            double p[CD];
            double s = 0.0;
            #pragma unroll
            for (int d = 0; d < CD; d++) { p[d] = sm.projs[r][d]; s += p[d] * p[d]; }
            const double m = fmax(sqrt(s), 1e-12);
            double pn[CD];
            #pragma unroll
            for (int d = 0; d < CD; d++) pn[d] = 2.0 * (p[d] / m);
            double best = -1e300;
            int bidx = 0;
            for (int k = 0; k < 16; k++) {
                const int c = k * 64 + tx;          // per-lane ascending scan
                const double* cr = cbn + (size_t)c * CD;
                double dot = cbn2[c];
                #pragma unroll
                for (int d = 0; d < CD; d++) dot = fma(pn[d], cr[d], dot);
                if (dot > best) { best = dot; bidx = c; }
            }
            #pragma unroll
            for (int off = 32; off; off >>= 1) {    // global first-max: max value, tie -> min index
                const double ov = __shfl_xor(best, off, 64);
                const int    oi = __shfl_xor(bidx, off, 64);
                if (ov > best || (ov == best && oi < bidx)) { best = ov; bidx = oi; }
            }
            if (tx == 0) sm.u.b.bfin[r] = bidx;
        }
    }
    __syncthreads();

    // finalize rows: index output, q_st, loss partial
    if (tid < TPB) {
        const int r = tid;
        const int bi = sm.u.b.bfin[r];
        idxf[bt0 + r] = (float)bi;
        const float* qr = cb + (size_t)bi * CD;
        double ls = 0.0;
        #pragma unroll
        for (int d = 0; d < CD; d++) {
            const float pf = (float)sm.projs[r][d];
            const float cf = qr[d];
            sm.u.b.qf[r][d] = pf + (cf - pf);       // straight-through forward value
            const float df = pf - cf;
            ls += (double)(df * df);
        }
        #pragma unroll
        for (int off = 32; off; off >>= 1) ls += __shfl_xor(ls, off, 64);
        if (tx == 0) atomicAdd(lossacc, ls);        // 2 atomics/block
    }
    __syncthreads();   // qf ready; loss atomics drained by barrier

    // ================= Phase C: out = q_st @ Wout^T + b  (identical rounding to prior K4) =================
    float q0[CD], q1[CD];
    #pragma unroll
    for (int d = 0; d < CD; d++) {
        q0[d] = sm.u.b.qf[tx * 2][d];
        q1[d] = sm.u.b.qf[tx * 2 + 1][d];
    }
    float* op = out + ((size_t)b * NH) * NT + t0 + tx * 2;
    #pragma unroll 4
    for (int i = 0; i < 128; i++) {
        const int h = h0 + i;
        const float* wr = wo + (size_t)h * CD;      // wave-uniform -> scalar loads
        float o0 = 0.f, o1 = 0.f;
        #pragma unroll
        for (int d = 0; d < CD; d++) {
            o0 = fmaf(q0[d], wr[d], o0);
            o1 = fmaf(q1[d], wr[d], o1);
        }
        const float bh = bo[h];
        o0 += bh; o1 += bh;
        *(float2*)(op + (size_t)h * NT) = make_float2(o0, o1);
    }

    // last block finalizes the loss scalars (no extra launch)
    if (tid == 0) {
        __threadfence();
        const unsigned v = atomicAdd(donecnt, 1u);
        if (v == GRID - 1) {
            const double tot = atomicAdd(lossacc, 0.0);   // atomic read of total
            const float lv = (float)(tot / (double)((size_t)NB * CD * NT));
            lossout[0] = lv;   // commitment_loss
            lossout[1] = lv;   // codebook_loss (identical forward value)
        }
    }
}

// ---------------- launch ----------------
extern "C" void kernel_launch(void* const* d_in, const int* in_sizes, int n_in,
                              void* d_out, int out_size, void* d_ws, size_t ws_size,
                              hipStream_t stream) {
    const float* hidden = (const float*)d_in[0];
    const float* ipw    = (const float*)d_in[1];
    const float* ipb    = (const float*)d_in[2];
    const float* opw    = (const float*)d_in[3];
    const float* opb    = (const float*)d_in[4];
    const float* cb     = (const float*)d_in[5];

    float* out      = (float*)d_out;                    // [NB][NH][NT]
    float* loss_out = out + (size_t)NB * NH * NT;       // 2 scalars
    float* idxf     = loss_out + 2;                     // [NB*NT]
    float* projf    = idxf + NBT;                       // [NB][CD][NT]

    double* Wt      = (double*)d_ws;                    // 8192
    double* biasd   = Wt + CD * NH;                     // 8
    double* cbn     = biasd + 8;                        // 8192
    double* cbn2    = cbn + (size_t)CS * CD;            // 1024
    double* lossacc = cbn2 + CS;                        // 1 (+7 pad)
    float*  cbnf    = (float*)(lossacc + 8);            // 8192 floats
    float*  cbn2f   = cbnf + (size_t)CS * CD;           // 1024 floats
    unsigned* donecnt = (unsigned*)(cbn2f + CS);        // 1

    k0_prep<<<32, 256, 0, stream>>>(ipw, ipb, cb, Wt, biasd, cbn, cbn2, cbnf, cbn2f,
                                    lossacc, donecnt);
    k_fused<<<GRID, dim3(64, 8), 0, stream>>>(hidden, Wt, biasd, cbn, cbn2, cbnf, cbn2f,
                                              cb, opw, opb, lossacc, donecnt,
                                              out, loss_out, idxf, projf);
}